// Round 11
// baseline (133.529 us; speedup 1.0000x reference)
//
#include <hip/hip_runtime.h>
#include <hip/hip_bf16.h>
#include <math.h>

#define MDIM 8192
#define NDIM 4096
#define KDIM 128
#define TPB 4       // tiles (128x128) per block
#define NBLK 1792   // 7168 tiles / TPB

typedef __bf16 bf16x8 __attribute__((ext_vector_type(8)));
typedef float f32x4 __attribute__((ext_vector_type(4)));

__device__ __forceinline__ unsigned short f32_to_bf16_rne(float f) {
  unsigned int u = __float_as_uint(f);
  u += 0x7fffu + ((u >> 16) & 1u);
  return (unsigned short)(u >> 16);
}

__global__ void convert_kernel(const float* __restrict__ X, unsigned short* __restrict__ Xb,
                               double* __restrict__ partial, int n4) {
  int tid = blockIdx.x * blockDim.x + threadIdx.x;
  int stride = gridDim.x * blockDim.x;
  float s = 0.f;
  const float4* X4 = (const float4*)X;
  ushort4* Xb4 = (ushort4*)Xb;
  for (int i = tid; i < n4; i += stride) {
    float4 v = X4[i];
    s += v.x * v.x + v.y * v.y + v.z * v.z + v.w * v.w;
    ushort4 p;
    p.x = f32_to_bf16_rne(v.x);
    p.y = f32_to_bf16_rne(v.y);
    p.z = f32_to_bf16_rne(v.z);
    p.w = f32_to_bf16_rne(v.w);
    Xb4[i] = p;
  }
  for (int off = 32; off > 0; off >>= 1) s += __shfl_down(s, off, 64);
  __shared__ float sw[4];
  int lane = threadIdx.x & 63, wid = threadIdx.x >> 6;
  if (lane == 0) sw[wid] = s;
  __syncthreads();
  if (threadIdx.x == 0) partial[blockIdx.x] = (double)(sw[0] + sw[1] + sw[2] + sw[3]);
}

// Flat 128x128-tile space over the three products (boundaries divisible by TPB):
//   t in [0,2048):      (Ub Vb^T vs A  )  64x32 tiles, ldT=4096
//   t in [2048,6144):   (Ub Ub^T vs S_m)  64x64 tiles, ldT=8192
//   t in [6144,7168):   (Vb Vb^T vs S_d)  32x32 tiles, ldT=4096
struct Ctx {
  const unsigned short* X;
  const unsigned short* Y;
  const float* T;
  int ldT, brow, bcol;
};

__device__ __forceinline__ Ctx ctx_of(int t, const unsigned short* Ub, const unsigned short* Vb,
                                      const float* A, const float* Sm, const float* Sd) {
  Ctx c;
  if (t < 2048) {
    c.X = Ub; c.Y = Vb; c.T = A; c.ldT = NDIM; c.brow = (t >> 5) * 128; c.bcol = (t & 31) * 128;
  } else if (t < 6144) {
    int u = t - 2048;
    c.X = Ub; c.Y = Ub; c.T = Sm; c.ldT = MDIM; c.brow = (u >> 6) * 128; c.bcol = (u & 63) * 128;
  } else {
    int u = t - 6144;
    c.X = Vb; c.Y = Vb; c.T = Sd; c.ldT = NDIM; c.brow = (u >> 5) * 128; c.bcol = (u & 31) * 128;
  }
  return c;
}

#define WAIT_VM(N) asm volatile("s_waitcnt vmcnt(" #N ")" ::: "memory")
#define SBAR() __builtin_amdgcn_sched_barrier(0)

// R11: one 512-thread block per CU (128KB LDS, ping-pong 64KB panel buffers),
// TPB tiles per block with a counted-vmcnt pipeline that never drains:
//   tile i: [barrier] issue panels(i+1)+T(i+1) -> vmcnt(24) [panels(i) done,
//   24 newer loads in flight] -> barrier -> MFMA(i) -> sync -> P-overlay into
//   dead panel buf -> sync -> vmcnt(16) [T(i) done] -> compare(i).
// All global accesses wave-contiguous full lines (R9-proven); MFMA operands
// via chunk-XOR-swizzled LDS (lgkmcnt, never touches the vmcnt queue).
__global__ __launch_bounds__(512, 1) void fused_all(
    const unsigned short* __restrict__ Ub,  // [M][128] bf16 bits
    const unsigned short* __restrict__ Vb,  // [N][128] bf16 bits
    const float* __restrict__ A,
    const float* __restrict__ S_m,
    const float* __restrict__ S_d,
    double* __restrict__ partial) {
  __shared__ __align__(16) char LDSc[131072];  // buf0: 0-64KB, buf1: 64-128KB
  __shared__ float swred[8];

  const int tid = threadIdx.x;
  const int lane = tid & 63;
  const int wid = tid >> 6;            // 0..7
  const int wr = wid >> 2, wc = wid & 3;  // wave tile: 64 rows x 32 cols
  const int l15 = lane & 15;
  const int lg = lane >> 4;            // 0..3
  const int j16 = lane & 15;           // 16B chunk for staging
  const int tr = tid >> 5;             // 0..15 (T rows)
  const int tc = tid & 31;             // 0..31 (T 16B chunks)

  const int t0 = blockIdx.x * TPB;
  float s = 0.f;

  f32x4 tA[8], tB[8];

  // ---- issue one tile's panels (8 gload_lds/wave) + T (8 loads/thread) ----
#define ISSUE(TT, BUFBASE, TREG)                                                       \
  {                                                                                    \
    Ctx cx = ctx_of((TT), Ub, Vb, A, S_m, S_d);                                        \
    _Pragma("unroll") for (int i = 0; i < 4; ++i) {                                    \
      const int rl = wid * 16 + i * 4 + lg;                                            \
      const unsigned short* gp = cx.X + (size_t)(cx.brow + rl) * KDIM +                \
                                 ((j16 ^ (rl & 7)) << 3);                              \
      __builtin_amdgcn_global_load_lds(                                                \
          (const __attribute__((address_space(1))) void*)gp,                           \
          (__attribute__((address_space(3))) void*)(LDSc + (BUFBASE) +                 \
                                                    (wid * 16 + i * 4) * 256),         \
          16, 0, 0);                                                                   \
    }                                                                                  \
    _Pragma("unroll") for (int i = 0; i < 4; ++i) {                                    \
      const int rl = wid * 16 + i * 4 + lg;                                            \
      const unsigned short* gp = cx.Y + (size_t)(cx.bcol + rl) * KDIM +                \
                                 ((j16 ^ (rl & 7)) << 3);                              \
      __builtin_amdgcn_global_load_lds(                                                \
          (const __attribute__((address_space(1))) void*)gp,                           \
          (__attribute__((address_space(3))) void*)(LDSc + (BUFBASE) + 32768 +         \
                                                    (wid * 16 + i * 4) * 256),         \
          16, 0, 0);                                                                   \
    }                                                                                  \
    SBAR();                                                                            \
    const int ld4 = cx.ldT >> 2;                                                       \
    const f32x4* Tb = (const f32x4*)cx.T + (size_t)cx.brow * ld4 + (cx.bcol >> 2);     \
    _Pragma("unroll") for (int it = 0; it < 8; ++it)                                   \
      TREG[it] = Tb[(size_t)(it * 16 + tr) * ld4 + tc];                                \
    SBAR();                                                                            \
  }

#define MFMA_PHASE(BUFBASE, ACC)                                                       \
  _Pragma("unroll") for (int kk = 0; kk < 4; ++kk) {                                   \
    const int c = kk * 4 + lg;                                                         \
    bf16x8 y[2], x[4];                                                                 \
    _Pragma("unroll") for (int p = 0; p < 2; ++p) {                                    \
      const int rl = wc * 32 + p * 16 + l15;                                           \
      y[p] = *(const bf16x8*)(LDSc + (BUFBASE) + 32768 + rl * 256 +                    \
                              ((c ^ (rl & 7)) << 4));                                  \
    }                                                                                  \
    _Pragma("unroll") for (int q = 0; q < 4; ++q) {                                    \
      const int rl = wr * 64 + q * 16 + l15;                                           \
      x[q] = *(const bf16x8*)(LDSc + (BUFBASE) + rl * 256 + ((c ^ (rl & 7)) << 4));    \
    }                                                                                  \
    _Pragma("unroll") for (int p = 0; p < 2; ++p)                                      \
      _Pragma("unroll") for (int q = 0; q < 4; ++q)                                    \
        ACC[p][q] = __builtin_amdgcn_mfma_f32_16x16x32_bf16(y[p], x[q], ACC[p][q],     \
                                                            0, 0, 0);                  \
  }

#define PWRITE(BUFBASE, ACC)                                                           \
  _Pragma("unroll") for (int q = 0; q < 4; ++q) {                                      \
    const int rp = wr * 64 + q * 16 + l15;                                             \
    _Pragma("unroll") for (int p = 0; p < 2; ++p) {                                    \
      const int cw = wc * 8 + p * 4 + lg;                                              \
      *(f32x4*)(LDSc + (BUFBASE) + rp * 512 + ((cw ^ (rp & 7)) << 4)) = ACC[p][q];     \
    }                                                                                  \
  }

#define COMPARE(BUFBASE, TREG)                                                         \
  _Pragma("unroll") for (int it = 0; it < 8; ++it) {                                   \
    const int r = it * 16 + tr;                                                        \
    const f32x4 pv = *(const f32x4*)(LDSc + (BUFBASE) + r * 512 +                      \
                                     ((tc ^ (r & 7)) << 4));                           \
    const f32x4 d = pv - TREG[it];                                                     \
    s += d[0] * d[0] + d[1] * d[1] + d[2] * d[2] + d[3] * d[3];                        \
  }

#define TILE_STEP(I, BUFBASE, NXTBASE, HASNEXT, VMA, VMD, TCUR, TNXT)                  \
  {                                                                                    \
    __builtin_amdgcn_s_barrier(); /* all waves done reading NXTBASE (prev P) */        \
    SBAR();                                                                            \
    if (HASNEXT) ISSUE(t0 + (I) + 1, NXTBASE, TNXT);                                   \
    WAIT_VM(VMA); /* panels(I) done; newer loads stay in flight */                     \
    SBAR();                                                                            \
    __builtin_amdgcn_s_barrier();                                                      \
    f32x4 acc[2][4] = {};                                                              \
    MFMA_PHASE(BUFBASE, acc);                                                          \
    __syncthreads(); /* panels(I) fully consumed */                                    \
    PWRITE(BUFBASE, acc);                                                              \
    __syncthreads();                                                                   \
    WAIT_VM(VMD); /* T(I) arrived */                                                   \
    SBAR();                                                                            \
    COMPARE(BUFBASE, TCUR);                                                            \
  }

  // prologue: fill the pipe with tile 0
  ISSUE(t0, 0, tA);
  // steady-state: issue(i+1) before waiting panels(i); counted vmcnt never drains
  TILE_STEP(0, 0, 65536, 1, 24, 16, tA, tB);
  TILE_STEP(1, 65536, 0, 1, 24, 16, tB, tA);
  TILE_STEP(2, 0, 65536, 1, 24, 16, tA, tB);
  TILE_STEP(3, 65536, 0, 0, 8, 0, tB, tA);

#undef TILE_STEP
#undef COMPARE
#undef PWRITE
#undef MFMA_PHASE
#undef ISSUE

  // deterministic block reduction (8 waves)
  for (int off = 32; off > 0; off >>= 1) s += __shfl_down(s, off, 64);
  if (lane == 0) swred[wid] = s;
  __syncthreads();
  if (tid == 0) {
    float tot = 0.f;
#pragma unroll
    for (int w = 0; w < 8; ++w) tot += swred[w];
    const int seg = (t0 < 2048) ? 0 : (t0 < 6144 ? 1 : 2);
    const double z = 0.0;
    partial[blockIdx.x]            = (seg == 0) ? (double)tot : z;
    partial[NBLK + blockIdx.x]     = (seg == 1) ? (double)tot : z;
    partial[2 * NBLK + blockIdx.x] = (seg == 2) ? (double)tot : z;
  }
}

// Deterministic final reduction of all partial arrays + scalar combine.
__global__ void finalize_kernel(const double* __restrict__ pr, int nr,
                                const double* __restrict__ psm, int nsm,
                                const double* __restrict__ psd, int nsd,
                                const double* __restrict__ pu, int nu,
                                const double* __restrict__ pv, int nv,
                                float* __restrict__ out) {
  __shared__ double sh[256];
  double sums[5];
  const double* ps[5] = {pr, psm, psd, pu, pv};
  int ns[5] = {nr, nsm, nsd, nu, nv};
  for (int q = 0; q < 5; ++q) {
    double s = 0.0;
    for (int i = threadIdx.x; i < ns[q]; i += 256) s += ps[q][i];
    sh[threadIdx.x] = s;
    __syncthreads();
    for (int k = 128; k > 0; k >>= 1) {
      if (threadIdx.x < k) sh[threadIdx.x] += sh[threadIdx.x + k];
      __syncthreads();
    }
    sums[q] = sh[0];
    __syncthreads();
  }
  if (threadIdx.x == 0) {
    double recon = sums[0] / ((double)MDIM * (double)NDIM);
    double res = recon + 0.01 * (sqrt(sums[3]) + sqrt(sums[4]) + sqrt(sums[1]) + sqrt(sums[2]));
    out[0] = (float)res;
  }
}

extern "C" void kernel_launch(void* const* d_in, const int* in_sizes, int n_in,
                              void* d_out, int out_size, void* d_ws, size_t ws_size,
                              hipStream_t stream) {
  const float* A   = (const float*)d_in[0];  // [M][N]
  const float* S_m = (const float*)d_in[1];  // [M][M]
  const float* S_d = (const float*)d_in[2];  // [N][N]
  const float* U   = (const float*)d_in[3];  // [M][K]
  const float* V   = (const float*)d_in[4];  // [N][K]

  char* ws = (char*)d_ws;
  unsigned short* Ubf = (unsigned short*)ws;                             // 2 MB
  unsigned short* Vbf = (unsigned short*)(ws + (size_t)2 * 1024 * 1024); // 1 MB
  double* pd = (double*)(ws + (size_t)3 * 1024 * 1024);
  double* p_all = pd;                // 3*NBLK
  double* p_u   = p_all + 3 * NBLK;  // 256
  double* p_v   = p_u + 256;         // 256

  convert_kernel<<<256, 256, 0, stream>>>(U, Ubf, p_u, MDIM * KDIM / 4);
  convert_kernel<<<256, 256, 0, stream>>>(V, Vbf, p_v, NDIM * KDIM / 4);

  fused_all<<<NBLK, 512, 0, stream>>>(Ubf, Vbf, A, S_m, S_d, p_all);

  finalize_kernel<<<1, 256, 0, stream>>>(p_all, NBLK, p_all + NBLK, NBLK, p_all + 2 * NBLK, NBLK,
                                         p_u, 256, p_v, 256, (float*)d_out);
}

// Round 12
// 116.460 us; speedup vs baseline: 1.1466x; 1.1466x over previous
//
#include <hip/hip_runtime.h>
#include <hip/hip_bf16.h>
#include <math.h>

#define MDIM 8192
#define NDIM 4096
#define KDIM 128

typedef __bf16 bf16x8 __attribute__((ext_vector_type(8)));
typedef float f32x4 __attribute__((ext_vector_type(4)));

__device__ __forceinline__ unsigned short f32_to_bf16_rne(float f) {
  unsigned int u = __float_as_uint(f);
  u += 0x7fffu + ((u >> 16) & 1u);
  return (unsigned short)(u >> 16);
}

// Convert f32 [R][128] -> bf16 packed in MFMA-fragment order, + sum of squares.
// Packed layout (halves): addr = (row>>4)*2048 + (k>>5)*512 + lane*8 + (k&7)
//   where lane = ((k>>3)&3)*16 + (row&15).
// A wave's fragment load in fused_all is then base + lane*16B = 1KB contiguous.
__global__ void convert_pack_kernel(const float* __restrict__ X, unsigned short* __restrict__ Xp,
                                    double* __restrict__ partial, int n4) {
  int tid = blockIdx.x * blockDim.x + threadIdx.x;
  int stride = gridDim.x * blockDim.x;
  float s = 0.f;
  const float4* X4 = (const float4*)X;
  for (int i = tid; i < n4; i += stride) {
    float4 v = X4[i];
    s += v.x * v.x + v.y 
* v.y + v.z * v.z + v.w * v.w;
    const int row = i >> 5;
    const int k4 = i & 31;        // float4 index within row; k = 4*k4
    const int k = k4 << 2;
    const int lane = (((k >> 3) & 3) << 4) | (row & 15);
    const size_t ha = (size_t)(row >> 4) * 2048 + ((k >> 5) << 9) + lane * 8 + (k & 7);
    ushort4 p;
    p.x = f32_to_bf16_rne(v.x);
    p.y = f32_to_bf16_rne(v.y);
    p.z = f32_to_bf16_rne(v.z);
    p.w = f32_to_bf16_rne(v.w);
    *(ushort4*)(Xp + ha) = p;
  }
  for (int off = 32; off > 0; off >>= 1) s += __shfl_down(s, off, 64);
  __shared__ float sw[4];
  int lane = threadIdx.x & 63, wid = threadIdx.x >> 6;
  if (lane == 0) sw[wid] = s;
  __syncthreads();
  if (threadIdx.x == 0) partial[blockIdx.x] = (double)(sw[0] + sw[1] + sw[2] + sw[3]);
}

// ALL THREE fused products, one 128x128 tile per block (merged 1D grid):
//   g in [0,2048):      (U V^T vs A  )  32 block-cols, ldT=4096
//   g in [2048,6144):   (U U^T vs S_m)  64 block-cols, ldT=8192
//   g in [6144,7168):   (V V^T vs S_d)  32 block-cols, ldT=4096
//
// R12: operands are PRE-PACKED in fragment order, so fragment loads are
// wave-contiguous full-line dwordx4 straight to registers — no panel LDS,
// no stage barrier, no ds_reads feeding MFMA. Issue order (sched_barrier
// pinned): 32 frag loads (L2-resident, head of vmcnt queue) -> 16 T
// global_load_lds (source XOR-swizzled; DMA writes LDS, zero VGPR) -> MFMA
// (counted vmcnt waits touch only frags; T stays in flight) -> syncthreads
// -> compare acc regs vs fragment-layout ds_reads of T.
__global__ __launch_bounds__(256, 2) void fused_all(
    const unsigned short* __restrict__ Up,  // packed U
    const unsigned short* __restrict__ Vp,  // packed V
    const float* __restrict__ A,
    const float* __restrict__ S_m,
    const float* __restrict__ S_d,
    double* __restrict__ partial) {
  __shared__ __align__(16) char LDSc[65536];  // T tile 128 x 512B
  __shared__ float swred[4];

  const int g = blockIdx.x;
  const unsigned short* Xp;
  const unsigned short* Yp;
  const float* T;
  int ldT, v, gc;
  if (g < 2048) {
    Xp = Up; Yp = Vp; T = A; ldT = NDIM; v = g; gc = 32;
  } else if (g < 6144) {
    Xp = Up; Yp = Up; T = S_m; ldT = MDIM; v = g - 2048; gc = 64;
  } else {
    Xp = Vp; Yp = Vp; T = S_d; ldT = NDIM; v = g - 6144; gc = 32;
  }
  const int r_blk = v / gc;
  const int c_blk = v - r_blk * gc;
  const int brow = r_blk * 128, bcol = c_blk * 128;

  const int tid = threadIdx.x;
  const int lane = tid & 63;
  const int wid = tid >> 6;
  const int wr = wid >> 1, wc = wid & 1;
  const int l15 = lane & 15;
  const int lg = lane >> 4;

  // ---- 1) fragment loads: wave-contiguous 1KB from packed operands ----
  const unsigned short* Xbase = Xp + (size_t)((brow >> 4) + wr * 4) * 2048 + lane * 8;
  const unsigned short* Ybase = Yp + (size_t)((bcol >> 4) + wc * 4) * 2048 + lane * 8;
  bf16x8 x[4][4], y[4][4];  // [kk][tile]
#pragma unroll
  for (int kk = 0; kk < 4; ++kk) {
#pragma unroll
    for (int q = 0; q < 4; ++q)
      x[kk][q] = *(const bf16x8*)(Xbase + (size_t)q * 2048 + (kk << 9));
#pragma unroll
    for (int p = 0; p < 4; ++p)
      y[kk][p] = *(const bf16x8*)(Ybase + (size_t)p * 2048 + (kk << 9));
  }
  __builtin_amdgcn_sched_barrier(0);

  // ---- 2) T tile -> LDS via DMA, wave-contiguous lines, source-swizzled ----
  // LDS[r][slot s] = T[r][chunk s ^ (r&7)]  (16B chunks, 32 per 512B row)
  {
    const int str = tid >> 5;  // 0..7: row within 8-row group
    const int stc = tid & 31;  // 16B chunk slot
#pragma unroll
    for (int it = 0; it < 16; ++it) {
      const int r = it * 8 + str;
      const float* gp = T + (size_t)(brow + r) * ldT + bcol + ((stc ^ (r & 7)) << 2);
      __builtin_amdgcn_global_load_lds(
          (const __attribute__((address_space(1))) void*)gp,
          (__attribute__((address_space(3))) void*)(LDSc + it * 4096 + wid * 1024 + (lane << 4)),
          16, 0, 0);
    }
  }
  __builtin_amdgcn_sched_barrier(0);

  // ---- 3) MFMA: pure-register operands; counted vmcnt waits only on frags ----
  f32x4 acc[4][4] = {};  // acc[p][q][j] = P[brow+wr*64+q*16+l15][bcol+wc*64+p*16+lg*4+j]
#pragma unroll
  for (int kk = 0; kk < 4; ++kk)
#pragma unroll
    for (int p = 0; p < 4; ++p)
#pragma unroll
      for (int q = 0; q < 4; ++q)
        acc[p][q] = __builtin_amdgcn_mfma_f32_16x16x32_bf16(y[kk][p], x[kk][q], acc[p][q], 0, 0, 0);

  // ---- 4) T landed (syncthreads drains vmcnt incl. the 16 DMA loads) ----
  __syncthreads();

  // ---- 5) compare acc registers vs fragment-layout reads of T in LDS ----
  float s = 0.f;
#pragma unroll
  for (int q = 0; q < 4; ++q) {
    const int r = wr * 64 + q * 16 + l15;
    const size_t rbase = (size_t)r * 512;
#pragma unroll
    for (int p = 0; p < 4; ++p) {
      const int c = wc * 16 + p * 4 + lg;  // 16B chunk within the row
      const f32x4 tv = *(const f32x4*)(LDSc + rbase + ((c ^ (r & 7)) << 4));
      const f32x4 d = acc[p][q] - tv;
      s += d[0] * d[0] + d[1] * d[1] + d[2] * d[2] + d[3] * d[3];
    }
  }

  // deterministic block reduction
  for (int off = 32; off > 0; off >>= 1) s += __shfl_down(s, off, 64);
  if (lane == 0) swred[wid] = s;
  __syncthreads();
  if (tid == 0)
    partial[g] = (double)(swred[0] + swred[1] + swred[2] + swred[3]);
}

// Deterministic final reduction of all partial arrays + scalar combine.
__global__ void finalize_kernel(const double* __restrict__ pr, int nr,
                                const double* __restrict__ psm, int nsm,
                                const double* __restrict__ psd, int nsd,
                                const double* __restrict__ pu, int nu,
                                const double* __restrict__ pv, int nv,
                                float* __restrict__ out) {
  __shared__ double sh[256];
  double sums[5];
  const double* ps[5] = {pr, psm, psd, pu, pv};
  int ns[5] = {nr, nsm, nsd, nu, nv};
  for (int q = 0; q < 5; ++q) {
    double s = 0.0;
    for (int i = threadIdx.x; i < ns[q]; i += 256) s += ps[q][i];
    sh[threadIdx.x] = s;
    __syncthreads();
    for (int k = 128; k > 0; k >>= 1) {
      if (threadIdx.x < k) sh[threadIdx.x] += sh[threadIdx.x + k];
      __syncthreads();
    }
    sums[q] = sh[0];
    __syncthreads();
  }
  if (threadIdx.x == 0) {
    double recon = sums[0] / ((double)MDIM * (double)NDIM);
    double res = recon + 0.01 * (sqrt(sums[3]) + sqrt(sums[4]) + sqrt(sums[1]) + sqrt(sums[2]));
    out[0] = (float)res;
  }
}

extern "C" void kernel_launch(void* const* d_in, const int* in_sizes, int n_in,
                              void* d_out, int out_size, void* d_ws, size_t ws_size,
                              hipStream_t stream) {
  const float* A   = (const float*)d_in[0];  // [M][N]
  const float* S_m = (const float*)d_in[1];  // [M][M]
  const float* S_d = (const float*)d_in[2];  // [N][N]
  const float* U   = (const float*)d_in[3];  // [M][K]
  const float* V   = (const float*)d_in[4];  // [N][K]

  char* ws = (char*)d_ws;
  unsigned short* Up = (unsigned short*)ws;                             // 2 MB
  unsigned short* Vp = (unsigned short*)(ws + (size_t)2 * 1024 * 1024); // 1 MB
  double* pd = (double*)(ws + (size_t)3 * 1024 * 1024);
  double* p_all = pd;            // 7168
  double* p_u   = p_all + 7168;  // 256
  double* p_v   = p_u + 256;     // 256

  convert_pack_kernel<<<256, 256, 0, stream>>>(U, Up, p_u, MDIM * KDIM / 4);
  convert_pack_kernel<<<256, 256, 0, stream>>>(V, Vp, p_v, NDIM * KDIM / 4);

  fused_all<<<7168, 256, 0, stream>>>(Up, Vp, A, S_m, S_d, p_all);

  finalize_kernel<<<1, 256, 0, stream>>>(p_all, 2048, p_all + 2048, 4096, p_all + 6144, 1024,
                                         p_u, 256, p_v, 256, (float*)d_out);
}

// Round 13
// 102.809 us; speedup vs baseline: 1.2988x; 1.1328x over previous
//
#include <hip/hip_runtime.h>
#include <hip/hip_bf16.h>
#include <math.h>

#define MDIM 8192
#define NDIM 4096
#define KDIM 128

typedef __bf16 bf16x8 __attribute__((ext_vector_type(8)));
typedef float f32x4 __attribute__((ext_vector_type(4)));

__device__ __forceinline__ unsigned short f32_to_bf16_rne(float f) {
  unsigned int u = __float_as_uint(f);
  u += 0x7fffu + ((u >> 16) & 1u);
  return (unsigned short)(u >> 16);
}

// Merged convert: blocks [0,256) handle U, [256,384) handle V.
// f32 -> bf16 row-major copy + sum of squares (for ||U||_F / ||V||_F).
__global__ void convert_merged(const float* __restrict__ U, const float* __restrict__ V,
                               unsigned short* __restrict__ Ub, unsigned short* __restrict__ Vb,
                               double* __restrict__ p_u, double* __restrict__ p_v) {
  const bool isV = blockIdx.x >= 256;
  const float4* X4 = (const float4*)(isV ? V : U);
  ushort4* Xb4 = (ushort4*)(isV ? Vb : Ub);
  const int n4 = isV ? (NDIM * KDIM / 4) : (MDIM * KDIM / 4);
  const int bid = isV ? (int)blockIdx.x - 256 : (int)blockIdx.x;
  const int nblk = isV ? 128 : 256;
  int i0 = bid * 256 + threadIdx.x;
  const int stride = nblk * 256;
  float s = 0.f;
  for (int i = i0; i < n4; i += stride) {
    float4 v = X4[i];
    s += v.x * v.x + v.y * v.y + v.z * v.z + v.w * v.w;
    ushort4 p;
    p.x = f32_to_bf16_rne(v.x);
    p.y = f32_to_bf16_rne(v.y);
    p.z = f32_to_bf16_rne(v.z);
    p.w = f32_to_bf16_rne(v.w);
    Xb4[i] = p;
  }
  for (int off = 32; off > 0; off >>= 1) s += __shfl_down(s, off, 64);
  __shared__ float sw[4];
  int lane = threadIdx.x & 63, wid = threadIdx.x >> 6;
  if (lane == 0) sw[wid] = s;
  __syncthreads();
  if (threadIdx.x == 0) {
    double r = (double)(sw[0] + sw[1] + sw[2] + sw[3]);
    if (isV) p_v[bid] = r; else p_u[bid] = r;
  }
}

// ALL THREE fused products, one 128x128 tile per block (merged 1D grid):
//   g in [0,2048):      (Ub Vb^T vs A  )  32 block-cols, ldT=4096
//   g in [2048,6144):   (Ub Ub^T vs S_m)  64 block-cols, ldT=8192
//   g in [6144,7168):   (Vb Vb^T vs S_d)  32 block-cols, ldT=4096
//
// R9-proven structure, with two fixes:
//  - vmcnt(16) not vmcnt(8): per wave 12 panel-DMAs + 16 T loads are
//    outstanding; waiting to 16 completes exactly the panels and leaves ALL
//    16 T loads in flight across MFMA+P-write (vmcnt(8) drained half the T
//    stream at the barrier = exposed HBM latency).
//  - T loads are NON-TEMPORAL: wave-contiguous full-line reads, each line
//    read exactly once -> nt stops the 448MB dead stream from churning
//    L2/LLC and evicting the hot Ub/Vb panels. (R4's nt failure was the
//    64B half-line granule, which this access pattern no longer has.)
__global__ __launch_bounds__(256, 2) void fused_all(
    const unsigned short* __restrict__ Ub,  // [M][128] bf16 bits
    const unsigned short* __restrict__ Vb,  // [N][128] bf16 bits
    const float* __restrict__ A,
    const float* __restrict__ S_m,
    const float* __restrict__ S_d,
    double* __restrict__ partial) {
  __shared__ float LDSf[16384];  // 64KB: panels (X:0-32KB, Y:32-64KB) then P
  char* LDSc = (char*)LDSf;

  const int g = blockIdx.x;
  const unsigned short* Xb;
  const unsigned short* Yb;
  const float* T;
  int ldT, v, gc;
  if (g < 2048) {
    Xb = Ub; Yb = Vb; T = A; ldT = NDIM; v = g; gc = 32;
  } else if (g < 6144) {
    Xb = Ub; Yb = Ub; T = S_m; ldT = MDIM; v = g - 2048; gc = 64;
  } else {
    Xb = Vb; Yb = Vb; T = S_d; ldT = NDIM; v = g - 6144; gc = 32;
  }
  const int r_blk = v / gc;
  const int c_blk = v - r_blk * gc;
  const int brow = r_blk * 128, bcol = c_blk * 128;

  const int tid = threadIdx.x;
  const int lane = tid & 63;
  const int wid = tid >> 6;
  const int wr = wid >> 1, wc = wid & 1;
  const int l15 = lane & 15;
  const int lg = lane >> 4;

  // ---- 1) stage X,Y panels to LDS: wave-linear dest, chunk-swizzled source ----
  // LDS[row][chunk j] = G[row][j ^ (row&7)]  (16B chunks, 16 per 256B row)
  {
    const int ro = lane >> 4;       // row within 4-row group
    const int j = lane & 15;        // 16B chunk within row
#pragma unroll
    for (int i = 0; i < 8; ++i) {
      const int rl = wid * 32 + i * 4 + ro;
      const unsigned short* gp = Xb + (size_t)(brow + rl) * KDIM + ((j ^ (rl & 7)) << 3);
      __builtin_amdgcn_global_load_lds(
          (const __attribute__((address_space(1))) void*)gp,
          (__attribute__((address_space(3))) void*)(LDSc + (wid * 32 + i * 4) * 256), 16, 0, 0);
    }
#pragma unroll
    for (int i = 0; i < 8; ++i) {
      const int rl = wid * 32 + i * 4 + ro;
      const unsigned short* gp = Yb + (size_t)(bcol + rl) * KDIM + ((j ^ (rl & 7)) << 3);
      __builtin_amdgcn_global_load_lds(
          (const __attribute__((address_space(1))) void*)gp,
          (__attribute__((address_space(3))) void*)(LDSc + 32768 + (wid * 32 + i * 4) * 256), 16, 0, 0);
    }
  }
  __builtin_amdgcn_sched_barrier(0);

  // ---- 2) T tile -> registers, wave-contiguous, NON-TEMPORAL ----
  const f32x4* Tb = (const f32x4*)T + (size_t)brow * (ldT >> 2) + (bcol >> 2);
  const int ldT4 = ldT >> 2;
  const int tr = tid >> 5, tc = tid & 31;  // 8 rows x 32 chunks per instr
  f32x4 t[16];
#pragma unroll
  for (int it = 0; it < 16; ++it)
    t[it] = __builtin_nontemporal_load(&Tb[(size_t)(it * 8 + tr) * ldT4 + tc]);
  __builtin_amdgcn_sched_barrier(0);

  // ---- panels done (ALL 16 T loads still in flight), all waves synced ----
  asm volatile("s_waitcnt vmcnt(16)" ::: "memory");
  __builtin_amdgcn_sched_barrier(0);
  __builtin_amdgcn_s_barrier();

  // ---- 3) MFMA phase: operands from LDS (lgkmcnt only — T never drained) ----
  f32x4 acc[4][4] = {};  // acc[p][q][reg] = P[wr*64+q*16+l15][wc*64+p*16+lg*4+reg]
#pragma unroll
  for (int kk = 0; kk < 4; ++kk) {
    const int c = kk * 4 + lg;  // 16B chunk within row
    bf16x8 y[4], x[4];
#pragma unroll
    for (int p = 0; p < 4; ++p) {
      const int rl = wc * 64 + p * 16 + l15;
      y[p] = *(const bf16x8*)(LDSc + 32768 + rl * 256 + ((c ^ (rl & 7)) << 4));
    }
#pragma unroll
    for (int q = 0; q < 4; ++q) {
      const int rl = wr * 64 + q * 16 + l15;
      x[q] = *(const bf16x8*)(LDSc + rl * 256 + ((c ^ (rl & 7)) << 4));
    }
#pragma unroll
    for (int p = 0; p < 4; ++p)
#pragma unroll
      for (int q = 0; q < 4; ++q)
        acc[p][q] = __builtin_amdgcn_mfma_f32_16x16x32_bf16(y[p], x[q], acc[p][q], 0, 0, 0);
  }

  // ---- 4) panels dead; overlay P into the same LDS (swizzled f32x4) ----
  __syncthreads();
#pragma unroll
  for (int q = 0; q < 4; ++q) {
    const int rp = wr * 64 + q * 16 + l15;
#pragma unroll
    for (int p = 0; p < 4; ++p) {
      const int cw = wc * 16 + p * 4 + lg;  // 16B chunk within 512B row
      *(f32x4*)(LDSc + rp * 512 + ((cw ^ (rp & 7)) << 4)) = acc[p][q];
    }
  }
  __syncthreads();

  // ---- 5) compare: wave-contiguous LDS reads vs register T ----
  float s = 0.f;
#pragma unroll
  for (int it = 0; it < 16; ++it) {
    const int r = it * 8 + tr;
    const f32x4 pv = *(const f32x4*)(LDSc + r * 512 + ((tc ^ (r & 7)) << 4));
    const f32x4 d = pv - t[it];
    s += d[0] * d[0] + d[1] * d[1] + d[2] * d[2] + d[3] * d[3];
  }

  // deterministic block reduction
  for (int off = 32; off > 0; off >>= 1) s += __shfl_down(s, off, 64);
  __shared__ float swred[4];
  if (lane == 0) swred[wid] = s;
  __syncthreads();
  if (tid == 0)
    partial[g] = (double)(swred[0] + swred[1] + swred[2] + swred[3]);
}

// Deterministic final reduction of all partial arrays + scalar combine.
__global__ void finalize_kernel(const double* __restrict__ pr, int nr,
                                const double* __restrict__ psm, int nsm,
                                const double* __restrict__ psd, int nsd,
                                const double* __restrict__ pu, int nu,
                                const double* __restrict__ pv, int nv,
                                float* __restrict__ out) {
  __shared__ double sh[256];
  double sums[5];
  const double* ps[5] = {pr, psm, psd, pu, pv};
  int ns[5] = {nr, nsm, nsd, nu, nv};
  for (int q = 0; q < 5; ++q) {
    double s = 0.0;
    for (int i = threadIdx.x; i < ns[q]; i += 256) s += ps[q][i];
    sh[threadIdx.x] = s;
    __syncthreads();
    for (int k = 128; k > 0; k >>= 1) {
      if (threadIdx.x < k) sh[threadIdx.x] += sh[threadIdx.x + k];
      __syncthreads();
    }
    sums[q] = sh[0];
    __syncthreads();
  }
  if (threadIdx.x == 0) {
    double recon = sums[0] / ((double)MDIM * (double)NDIM);
    double res = recon + 0.01 * (sqrt(sums[3]) + sqrt(sums[4]) + sqrt(sums[1]) + sqrt(sums[2]));
    out[0] = (float)res;
  }
}

extern "C" void kernel_launch(void* const* d_in, const int* in_sizes, int n_in,
                              void* d_out, int out_size, void* d_ws, size_t ws_size,
                              hipStream_t stream) {
  const float* A   = (const float*)d_in[0];  // [M][N]
  const float* S_m = (const float*)d_in[1];  // [M][M]
  const float* S_d = (const float*)d_in[2];  // [N][N]
  const float* U   = (const float*)d_in[3];  // [M][K]
  const float* V   = (const float*)d_in[4];  // [N][K]

  char* ws = (char*)d_ws;
  unsigned short* Ub = (unsigned short*)ws;                             // 2 MB
  unsigned short* Vb = (unsigned short*)(ws + (size_t)2 * 1024 * 1024); // 1 MB
  double* pd = (double*)(ws + (size_t)3 * 1024 * 1024);
  double* p_all = pd;            // 7168: [0,2048) recon | [2048,6144) S_m | [6144,7168) S_d
  double* p_u   = p_all + 7168;  // 256
  double* p_v   = p_u + 256;     // 128

  convert_merged<<<384, 256, 0, stream>>>(U, V, Ub, Vb, p_u, p_v);

  fused_all<<<7168, 256, 0, stream>>>(Ub, Vb, A, S_m, S_d, p_all);

  finalize_kernel<<<1, 256, 0, stream>>>(p_all, 2048, p_all + 2048, 4096, p_all + 6144, 1024,
                                         p_u, 256, p_v, 128, (float*)d_out);
}